// Round 4
// baseline (294.886 us; speedup 1.0000x reference)
//
#include <hip/hip_runtime.h>

#define DEVFN __device__ __forceinline__

typedef __attribute__((ext_vector_type(8))) __bf16 bf16x8;
typedef __attribute__((ext_vector_type(16))) float f32x16;
typedef unsigned short ushort;

DEVFN float sigmoidf_(float x) { return 1.f / (1.f + __expf(-x)); }

DEVFN ushort f2bf(float f) {   // RNE float->bf16
    unsigned u = __float_as_uint(f);
    unsigned r = (u + 0x7FFF + ((u >> 16) & 1)) >> 16;
    return (ushort)r;
}

// ---------------- correlation, barrier-free, direct loads ----------------
// Thread owns 4 px (float4). Per channel: 1 f1 float4 + NOFF*3 predicated f2
// float4 loads (window x0-4..x0+7), 16*NOFF^2 FMAs. Chunk partials striped
// across NSLICE output slices, combined in xbuild.
template<int C, int CC, int H, int W, int NOFF, int OFS, int NSLICE, int UNR>
__global__ void corr_kernel(const float* __restrict__ f1, const float* __restrict__ f2,
                            float* __restrict__ accout) {
    constexpr int HW = H * W;
    constexpr bool NEEDHI = (NOFF - 1 - OFS) >= 1;
    const int t     = threadIdx.x;
    const int px    = blockIdx.x * 1024 + t * 4;
    const int b     = blockIdx.y;
    const int chunk = blockIdx.z;
    const int y  = px / W;
    const int x0 = px - y * W;

    const float* f1p = f1 + ((size_t)b * C + chunk * CC) * HW + px;
    const float* f2b = f2 + ((size_t)b * C + chunk * CC) * HW;

    float acc[NOFF][NOFF][4];
#pragma unroll
    for (int i = 0; i < NOFF; ++i)
#pragma unroll
        for (int j = 0; j < NOFF; ++j)
#pragma unroll
            for (int p = 0; p < 4; ++p) acc[i][j][p] = 0.f;

#pragma unroll UNR
    for (int c = 0; c < CC; ++c) {
        float f1a[4];
        *reinterpret_cast<float4*>(f1a) = *reinterpret_cast<const float4*>(f1p + (size_t)c * HW);
        const float* f2c = f2b + (size_t)c * HW;
#pragma unroll
        for (int dyi = 0; dyi < NOFF; ++dyi) {
            const int yy = y + dyi - OFS;
            const bool rv = (yy >= 0) && (yy < H);
            const float* rp = f2c + yy * W + x0;
            float w[12];
            float4 z = make_float4(0.f, 0.f, 0.f, 0.f);
            float4 lo  = (rv && x0 >= 4)    ? *reinterpret_cast<const float4*>(rp - 4) : z;
            float4 mid = rv                 ? *reinterpret_cast<const float4*>(rp)     : z;
            float4 hi  = (NEEDHI && rv && (x0 + 4 < W)) ? *reinterpret_cast<const float4*>(rp + 4) : z;
            *reinterpret_cast<float4*>(&w[0]) = lo;
            *reinterpret_cast<float4*>(&w[4]) = mid;
            *reinterpret_cast<float4*>(&w[8]) = hi;
#pragma unroll
            for (int dxi = 0; dxi < NOFF; ++dxi)
#pragma unroll
                for (int p = 0; p < 4; ++p)
                    acc[dyi][dxi][p] = fmaf(f1a[p], w[4 + p + dxi - OFS], acc[dyi][dxi][p]);
        }
    }

    const int slice = chunk & (NSLICE - 1);
    float* ao = accout + ((size_t)(slice * 2 + b) * NOFF * NOFF) * HW + px;
#pragma unroll
    for (int dyi = 0; dyi < NOFF; ++dyi)
#pragma unroll
        for (int dxi = 0; dxi < NOFF; ++dxi) {
            float* p4 = ao + (size_t)(dyi * NOFF + dxi) * HW;
#pragma unroll
            for (int p = 0; p < 4; ++p) atomicAdd(p4 + p, acc[dyi][dxi][p]);
        }
}

// ---------------- build conv input: Xin[b][y][x][ic128] bf16 ----------------
template<int H, int W, int SCALE, int SHIFT, int NOFF, int OFS, int NSLICE>
__global__ void xbuild_kernel(const float* __restrict__ corr_acc, const float* __restrict__ h_pre,
                              ushort* __restrict__ Xin) {
    const int HW = H * W;
    int i = blockIdx.x * 256 + threadIdx.x;
    if (i >= 2 * HW * 16) return;
    int g  = i & 15;
    int px = (i >> 4) % HW;
    int b  = (i >> 4) / HW;
    int y = px / W, x = px - y * W;
    ushort out8[8];
#pragma unroll
    for (int j = 0; j < 8; ++j) {
        int ic = g * 8 + j;
        float v = 0.f;
        if (ic < 49) {
            int pi = ic / 7, pj = ic - pi * 7;
            int dy = pi - 3, dx = pj - 3;
            int uy = SCALE * y + dy, ux = SCALE * x + dx;
            if (uy >= 0 && uy < SCALE * H && ux >= 0 && ux < SCALE * W) {
                int idy = (dy >> SHIFT) + OFS;
                int idx = (dx >> SHIFT) + OFS;
                float cv = 0.f;
#pragma unroll
                for (int s = 0; s < NSLICE; ++s)
                    cv += corr_acc[((size_t)(s * 2 + b) * NOFF * NOFF + idy * NOFF + idx) * HW + px];
                v = cv >= 0.f ? cv : 0.01f * cv;
            }
        } else if (ic < 98) {
            v = h_pre[((size_t)b * 49 + (ic - 49)) * HW + px];
        }
        out8[j] = f2bf(v);
    }
    *reinterpret_cast<uint4*>(Xin + (size_t)i * 8) = *reinterpret_cast<uint4*>(out8);
}

// ---------------- weight prep: Wmf[tap9][icg16][oc256][8] bf16 (both levels) ----
__global__ void wprep_kernel(const float* __restrict__ w0, const float* __restrict__ w1,
                             ushort* __restrict__ Wmf0, ushort* __restrict__ Wmf1) {
    const float* w = blockIdx.y ? w1 : w0;
    ushort* Wmf    = blockIdx.y ? Wmf1 : Wmf0;
    int i = blockIdx.x * 256 + threadIdx.x;
    const int n = 9 * 16 * 256 * 8;
    if (i >= n) return;
    int iEl = i & 7;
    int oc  = (i >> 3) & 255;
    int icg = (i >> 11) & 15;
    int tap = i >> 15;
    int ic  = icg * 8 + iEl;
    float v = (oc < 196 && ic < 98) ? w[((size_t)oc * 98 + ic) * 9 + tap] : 0.f;
    Wmf[i] = f2bf(v);
}

// ---------------- conv3x3 via mfma_f32_32x32x16_bf16 ----------------
template<int H, int W, int SPLIT, int ICPS, int NKC, int STRIDE>
__global__ void convmf_kernel(const ushort* __restrict__ Xin, const ushort* __restrict__ Wmf,
                              float* __restrict__ Y) {
    const int HW = H * W;
    __shared__ ushort Xs[180 * STRIDE];
    const int tilesx = W / 16;
    const int by0 = (blockIdx.x / tilesx) * 8;
    const int bx0 = (blockIdx.x % tilesx) * 16;
    const int ocb = blockIdx.y * 64;
    const int b   = blockIdx.z & 1;
    const int s   = blockIdx.z >> 1;
    const int t   = threadIdx.x;
    const int wv  = t >> 6;
    const int l   = t & 63;
    const int G   = ICPS / 8;

    for (int u = t; u < 180 * G; u += 256) {
        int px = u / G, g = u - px * G;
        int gy = by0 + px / 18 - 1;
        int gx = bx0 + px % 18 - 1;
        uint4 v = make_uint4(0u, 0u, 0u, 0u);
        if (gy >= 0 && gy < H && gx >= 0 && gx < W)
            v = *reinterpret_cast<const uint4*>(Xin + (((size_t)b * HW + gy * W + gx) * 128 + s * ICPS + g * 8));
        *reinterpret_cast<uint4*>(&Xs[px * STRIDE + g * 8]) = v;
    }
    __syncthreads();

    f32x16 acc0 = {};
    f32x16 acc1 = {};
    const int n    = l & 31;
    const int hi   = l >> 5;
    const int wrow = 2 * wv + (n >> 4);
    const int wcol = n & 15;

#pragma unroll 1
    for (int kc = 0; kc < NKC; ++kc) {
        bf16x8 af[2][9];
        const int icg = (s * ICPS + kc * 16) / 8 + hi;
        const ushort* wp = Wmf + ((size_t)icg * 256 + ocb + n) * 8;
#pragma unroll
        for (int j = 0; j < 9; ++j) {
            af[0][j] = *reinterpret_cast<const bf16x8*>(wp + (size_t)j * 16 * 256 * 8);
            af[1][j] = *reinterpret_cast<const bf16x8*>(wp + (size_t)j * 16 * 256 * 8 + 32 * 8);
        }
#pragma unroll
        for (int j = 0; j < 9; ++j) {
            const int ky = j / 3, kx = j - (j / 3) * 3;
            const int hp = (wrow + ky) * 18 + wcol + kx;
            bf16x8 bf = *reinterpret_cast<const bf16x8*>(&Xs[hp * STRIDE + kc * 16 + hi * 8]);
            acc0 = __builtin_amdgcn_mfma_f32_32x32x16_bf16(af[0][j], bf, acc0, 0, 0, 0);
            acc1 = __builtin_amdgcn_mfma_f32_32x32x16_bf16(af[1][j], bf, acc1, 0, 0, 0);
        }
    }

    float* Yo = Y + ((size_t)(s * 2 + b) * 196) * HW;
    const int po = (by0 + wrow) * W + bx0 + wcol;
#pragma unroll
    for (int r = 0; r < 16; ++r) {
        int m = (r & 3) + 8 * (r >> 2) + 4 * hi;
        int oc0 = ocb + m;
        if (oc0 < 196) Yo[(size_t)oc0 * HW + po] = acc0[r];
        int oc1 = ocb + 32 + m;
        if (oc1 < 196) Yo[(size_t)oc1 * HW + po] = acc1[r];
    }
}

// ---------------- LSTM gates (split-reduce + bias + elementwise) ----------------
template<int S, int HW>
__global__ void lstm_kernel(const float* __restrict__ Y, const float* __restrict__ bias,
                            const float* __restrict__ c_pre,
                            float* __restrict__ h_out, float* __restrict__ c_out) {
    int i = blockIdx.x * 256 + threadIdx.x;
    const int n = 2 * 49 * HW;
    if (i >= n) return;
    int b   = i / (49 * HW);
    int rem = i - b * (49 * HW);
    int k   = rem / HW;
    float g4[4];
#pragma unroll
    for (int gi = 0; gi < 4; ++gi) {
        float v = bias[gi * 49 + k];
#pragma unroll
        for (int ss = 0; ss < S; ++ss)
            v += Y[((size_t)((ss * 2 + b) * 196) + gi * 49) * HW + rem];
        g4[gi] = v;
    }
    float iv = sigmoidf_(g4[0]);
    float fv = sigmoidf_(g4[1]);
    float ov = sigmoidf_(g4[2]);
    float gv = tanhf(g4[3]);
    float cp = c_pre[i];
    float cn = fv * cp + iv * gv;
    h_out[i] = ov * tanhf(cn);
    c_out[i] = cn;
}

extern "C" void kernel_launch(void* const* d_in, const int* in_sizes, int n_in,
                              void* d_out, int out_size, void* d_ws, size_t ws_size,
                              hipStream_t stream) {
    (void)in_sizes; (void)n_in; (void)out_size; (void)ws_size;
    const float* x0  = (const float*)d_in[0];
    const float* x1  = (const float*)d_in[1];
    const float* xp0 = (const float*)d_in[2];
    const float* xp1 = (const float*)d_in[3];
    const float* h0  = (const float*)d_in[4];
    const float* c0  = (const float*)d_in[5];
    const float* h1  = (const float*)d_in[6];
    const float* c1  = (const float*)d_in[7];
    const float* w0  = (const float*)d_in[8];
    const float* b0  = (const float*)d_in[9];
    const float* w1  = (const float*)d_in[10];
    const float* b1  = (const float*)d_in[11];
    float* out = (float*)d_out;

    // workspace layout (floats)
    float* ws = (float*)d_ws;
    float*  Wmf0f = ws;                  // 147456
    float*  Wmf1f = Wmf0f + 147456;      // 147456
    float*  Xin0f = Wmf1f + 147456;      // 524288
    float*  Xin1f = Xin0f + 524288;      // 131072
    float*  Y0    = Xin1f + 131072;      // 3211264
    float*  Y1    = Y0 + 3211264;        // 1605632
    // corr slice buffers alias Y0 (consumed by xbuild before conv writes Y0)
    float*  accC0s = Y0;                 // 4*2*16*4096 = 524288
    float*  accC1s = Y0 + 524288;        // 4*2*4*1024  = 32768
    ushort* Wmf0 = (ushort*)Wmf0f;
    ushort* Wmf1 = (ushort*)Wmf1f;
    ushort* Xin0 = (ushort*)Xin0f;
    ushort* Xin1 = (ushort*)Xin1f;

    hipMemsetAsync(accC0s, 0, (size_t)(524288 + 32768) * sizeof(float), stream);

    wprep_kernel<<<dim3(1152, 2), 256, 0, stream>>>(w0, w1, Wmf0, Wmf1);

    // level 0: C=512, 64x64, NOFF=4, OFS=2, CC=8 -> 64 chunks, 512 blocks
    corr_kernel<512, 8, 64, 64, 4, 2, 4, 2><<<dim3(4, 2, 64), 256, 0, stream>>>(x0, xp0, accC0s);
    // level 1: C=1024, 32x32, NOFF=2, OFS=1, CC=8 -> 128 chunks, 256 blocks
    corr_kernel<1024, 8, 32, 32, 2, 1, 4, 4><<<dim3(1, 2, 128), 256, 0, stream>>>(x1, xp1, accC1s);

    xbuild_kernel<64, 64, 2, 1, 4, 2, 4><<<512, 256, 0, stream>>>(accC0s, h0, Xin0);
    xbuild_kernel<32, 32, 4, 2, 2, 1, 4><<<128, 256, 0, stream>>>(accC1s, h1, Xin1);

    convmf_kernel<64, 64, 2, 64, 4, 72><<<dim3(32, 4, 4), 256, 0, stream>>>(Xin0, Wmf0, Y0);
    convmf_kernel<32, 32, 4, 32, 2, 40><<<dim3(8, 4, 8), 256, 0, stream>>>(Xin1, Wmf1, Y1);

    lstm_kernel<2, 4096><<<1568, 256, 0, stream>>>(Y0, b0, c0, out + 0,      out + 401408);
    lstm_kernel<4, 1024><<<392,  256, 0, stream>>>(Y1, b1, c1, out + 802816, out + 903168);
}

// Round 5
// 221.403 us; speedup vs baseline: 1.3319x; 1.3319x over previous
//
#include <hip/hip_runtime.h>

#define DEVFN __device__ __forceinline__

typedef __attribute__((ext_vector_type(8))) __bf16 bf16x8;
typedef __attribute__((ext_vector_type(16))) float f32x16;
typedef unsigned short ushort;

DEVFN float sigmoidf_(float x) { return 1.f / (1.f + __expf(-x)); }

DEVFN ushort f2bf(float f) {   // RNE float->bf16
    unsigned u = __float_as_uint(f);
    unsigned r = (u + 0x7FFF + ((u >> 16) & 1)) >> 16;
    return (ushort)r;
}

// ---------------- correlation, barrier-free, slice-store (NO atomics) ----------
// Thread owns 4 px (float4). Per channel: 1 f1 float4 + NOFF*3 predicated f2
// float4 loads, 16*NOFF^2 FMAs. Each (chunk,b) block writes its partial sums
// to an exclusive slice: slices[chunk][b][off][px]. Summed by reduce_kernel.
template<int C, int CC, int H, int W, int NOFF, int OFS, int UNR>
__global__ void corr_kernel(const float* __restrict__ f1, const float* __restrict__ f2,
                            float* __restrict__ slices) {
    constexpr int HW = H * W;
    constexpr bool NEEDHI = (NOFF - 1 - OFS) >= 1;
    const int t     = threadIdx.x;
    const int px    = blockIdx.x * 1024 + t * 4;
    const int b     = blockIdx.y;
    const int chunk = blockIdx.z;
    const int y  = px / W;
    const int x0 = px - y * W;

    const float* f1p = f1 + ((size_t)b * C + chunk * CC) * HW + px;
    const float* f2b = f2 + ((size_t)b * C + chunk * CC) * HW;

    float acc[NOFF][NOFF][4];
#pragma unroll
    for (int i = 0; i < NOFF; ++i)
#pragma unroll
        for (int j = 0; j < NOFF; ++j)
#pragma unroll
            for (int p = 0; p < 4; ++p) acc[i][j][p] = 0.f;

#pragma unroll UNR
    for (int c = 0; c < CC; ++c) {
        float f1a[4];
        *reinterpret_cast<float4*>(f1a) = *reinterpret_cast<const float4*>(f1p + (size_t)c * HW);
        const float* f2c = f2b + (size_t)c * HW;
#pragma unroll
        for (int dyi = 0; dyi < NOFF; ++dyi) {
            const int yy = y + dyi - OFS;
            const bool rv = (yy >= 0) && (yy < H);
            const float* rp = f2c + yy * W + x0;
            float w[12];
            float4 z = make_float4(0.f, 0.f, 0.f, 0.f);
            float4 lo  = (rv && x0 >= 4)    ? *reinterpret_cast<const float4*>(rp - 4) : z;
            float4 mid = rv                 ? *reinterpret_cast<const float4*>(rp)     : z;
            float4 hi  = (NEEDHI && rv && (x0 + 4 < W)) ? *reinterpret_cast<const float4*>(rp + 4) : z;
            *reinterpret_cast<float4*>(&w[0]) = lo;
            *reinterpret_cast<float4*>(&w[4]) = mid;
            *reinterpret_cast<float4*>(&w[8]) = hi;
#pragma unroll
            for (int dxi = 0; dxi < NOFF; ++dxi)
#pragma unroll
                for (int p = 0; p < 4; ++p)
                    acc[dyi][dxi][p] = fmaf(f1a[p], w[4 + p + dxi - OFS], acc[dyi][dxi][p]);
        }
    }

    float* ao = slices + ((size_t)(chunk * 2 + b) * NOFF * NOFF) * HW + px;
#pragma unroll
    for (int dyi = 0; dyi < NOFF; ++dyi)
#pragma unroll
        for (int dxi = 0; dxi < NOFF; ++dxi)
            *reinterpret_cast<float4*>(ao + (size_t)(dyi * NOFF + dxi) * HW) =
                make_float4(acc[dyi][dxi][0], acc[dyi][dxi][1], acc[dyi][dxi][2], acc[dyi][dxi][3]);
}

// ---------------- slice reduction: base[i] = sum_s slices[s*STRIDE + i] ------
template<int S, int STRIDE>
__global__ void reduce_kernel(const float* __restrict__ in, float* __restrict__ out) {
    const int i = (blockIdx.x * 256 + threadIdx.x) * 4;
    if (i >= STRIDE) return;
    float sx = 0.f, sy = 0.f, sz = 0.f, sw = 0.f;
#pragma unroll 8
    for (int k = 0; k < S; ++k) {
        float4 v = *reinterpret_cast<const float4*>(in + (size_t)k * STRIDE + i);
        sx += v.x; sy += v.y; sz += v.z; sw += v.w;
    }
    *reinterpret_cast<float4*>(out + i) = make_float4(sx, sy, sz, sw);
}

// ---------------- build conv input: Xin[b][y][x][ic128] bf16 ----------------
template<int H, int W, int SCALE, int SHIFT, int NOFF, int OFS>
__global__ void xbuild_kernel(const float* __restrict__ base, const float* __restrict__ h_pre,
                              ushort* __restrict__ Xin) {
    const int HW = H * W;
    int i = blockIdx.x * 256 + threadIdx.x;
    if (i >= 2 * HW * 16) return;
    int g  = i & 15;
    int px = (i >> 4) % HW;
    int b  = (i >> 4) / HW;
    int y = px / W, x = px - y * W;
    ushort out8[8];
#pragma unroll
    for (int j = 0; j < 8; ++j) {
        int ic = g * 8 + j;
        float v = 0.f;
        if (ic < 49) {
            int pi = ic / 7, pj = ic - pi * 7;
            int dy = pi - 3, dx = pj - 3;
            int uy = SCALE * y + dy, ux = SCALE * x + dx;
            if (uy >= 0 && uy < SCALE * H && ux >= 0 && ux < SCALE * W) {
                int idy = (dy >> SHIFT) + OFS;
                int idx = (dx >> SHIFT) + OFS;
                float cv = base[((size_t)b * NOFF * NOFF + idy * NOFF + idx) * HW + px];
                v = cv >= 0.f ? cv : 0.01f * cv;
            }
        } else if (ic < 98) {
            v = h_pre[((size_t)b * 49 + (ic - 49)) * HW + px];
        }
        out8[j] = f2bf(v);
    }
    *reinterpret_cast<uint4*>(Xin + (size_t)i * 8) = *reinterpret_cast<uint4*>(out8);
}

// ---------------- weight prep: Wmf[tap9][icg16][oc256][8] bf16 (both levels) ----
__global__ void wprep_kernel(const float* __restrict__ w0, const float* __restrict__ w1,
                             ushort* __restrict__ Wmf0, ushort* __restrict__ Wmf1) {
    const float* w = blockIdx.y ? w1 : w0;
    ushort* Wmf    = blockIdx.y ? Wmf1 : Wmf0;
    int i = blockIdx.x * 256 + threadIdx.x;
    const int n = 9 * 16 * 256 * 8;
    if (i >= n) return;
    int iEl = i & 7;
    int oc  = (i >> 3) & 255;
    int icg = (i >> 11) & 15;
    int tap = i >> 15;
    int ic  = icg * 8 + iEl;
    float v = (oc < 196 && ic < 98) ? w[((size_t)oc * 98 + ic) * 9 + tap] : 0.f;
    Wmf[i] = f2bf(v);
}

// ---------------- conv3x3 via mfma_f32_32x32x16_bf16 ----------------
template<int H, int W, int SPLIT, int ICPS, int NKC, int STRIDE>
__global__ void convmf_kernel(const ushort* __restrict__ Xin, const ushort* __restrict__ Wmf,
                              float* __restrict__ Y) {
    const int HW = H * W;
    __shared__ ushort Xs[180 * STRIDE];
    const int tilesx = W / 16;
    const int by0 = (blockIdx.x / tilesx) * 8;
    const int bx0 = (blockIdx.x % tilesx) * 16;
    const int ocb = blockIdx.y * 64;
    const int b   = blockIdx.z & 1;
    const int s   = blockIdx.z >> 1;
    const int t   = threadIdx.x;
    const int wv  = t >> 6;
    const int l   = t & 63;
    const int G   = ICPS / 8;

    for (int u = t; u < 180 * G; u += 256) {
        int px = u / G, g = u - px * G;
        int gy = by0 + px / 18 - 1;
        int gx = bx0 + px % 18 - 1;
        uint4 v = make_uint4(0u, 0u, 0u, 0u);
        if (gy >= 0 && gy < H && gx >= 0 && gx < W)
            v = *reinterpret_cast<const uint4*>(Xin + (((size_t)b * HW + gy * W + gx) * 128 + s * ICPS + g * 8));
        *reinterpret_cast<uint4*>(&Xs[px * STRIDE + g * 8]) = v;
    }
    __syncthreads();

    f32x16 acc0 = {};
    f32x16 acc1 = {};
    const int n    = l & 31;
    const int hi   = l >> 5;
    const int wrow = 2 * wv + (n >> 4);
    const int wcol = n & 15;

#pragma unroll 1
    for (int kc = 0; kc < NKC; ++kc) {
        bf16x8 af[2][9];
        const int icg = (s * ICPS + kc * 16) / 8 + hi;
        const ushort* wp = Wmf + ((size_t)icg * 256 + ocb + n) * 8;
#pragma unroll
        for (int j = 0; j < 9; ++j) {
            af[0][j] = *reinterpret_cast<const bf16x8*>(wp + (size_t)j * 16 * 256 * 8);
            af[1][j] = *reinterpret_cast<const bf16x8*>(wp + (size_t)j * 16 * 256 * 8 + 32 * 8);
        }
#pragma unroll
        for (int j = 0; j < 9; ++j) {
            const int ky = j / 3, kx = j - (j / 3) * 3;
            const int hp = (wrow + ky) * 18 + wcol + kx;
            bf16x8 bf = *reinterpret_cast<const bf16x8*>(&Xs[hp * STRIDE + kc * 16 + hi * 8]);
            acc0 = __builtin_amdgcn_mfma_f32_32x32x16_bf16(af[0][j], bf, acc0, 0, 0, 0);
            acc1 = __builtin_amdgcn_mfma_f32_32x32x16_bf16(af[1][j], bf, acc1, 0, 0, 0);
        }
    }

    float* Yo = Y + ((size_t)(s * 2 + b) * 196) * HW;
    const int po = (by0 + wrow) * W + bx0 + wcol;
#pragma unroll
    for (int r = 0; r < 16; ++r) {
        int m = (r & 3) + 8 * (r >> 2) + 4 * hi;
        int oc0 = ocb + m;
        if (oc0 < 196) Yo[(size_t)oc0 * HW + po] = acc0[r];
        int oc1 = ocb + 32 + m;
        if (oc1 < 196) Yo[(size_t)oc1 * HW + po] = acc1[r];
    }
}

// ---------------- LSTM gates (split-reduce + bias + elementwise) ----------------
template<int S, int HW>
__global__ void lstm_kernel(const float* __restrict__ Y, const float* __restrict__ bias,
                            const float* __restrict__ c_pre,
                            float* __restrict__ h_out, float* __restrict__ c_out) {
    int i = blockIdx.x * 256 + threadIdx.x;
    const int n = 2 * 49 * HW;
    if (i >= n) return;
    int b   = i / (49 * HW);
    int rem = i - b * (49 * HW);
    int k   = rem / HW;
    float g4[4];
#pragma unroll
    for (int gi = 0; gi < 4; ++gi) {
        float v = bias[gi * 49 + k];
#pragma unroll
        for (int ss = 0; ss < S; ++ss)
            v += Y[((size_t)((ss * 2 + b) * 196) + gi * 49) * HW + rem];
        g4[gi] = v;
    }
    float iv = sigmoidf_(g4[0]);
    float fv = sigmoidf_(g4[1]);
    float ov = sigmoidf_(g4[2]);
    float gv = tanhf(g4[3]);
    float cp = c_pre[i];
    float cn = fv * cp + iv * gv;
    h_out[i] = ov * tanhf(cn);
    c_out[i] = cn;
}

extern "C" void kernel_launch(void* const* d_in, const int* in_sizes, int n_in,
                              void* d_out, int out_size, void* d_ws, size_t ws_size,
                              hipStream_t stream) {
    (void)in_sizes; (void)n_in; (void)out_size; (void)ws_size;
    const float* x0  = (const float*)d_in[0];
    const float* x1  = (const float*)d_in[1];
    const float* xp0 = (const float*)d_in[2];
    const float* xp1 = (const float*)d_in[3];
    const float* h0  = (const float*)d_in[4];
    const float* c0  = (const float*)d_in[5];
    const float* h1  = (const float*)d_in[6];
    const float* c1  = (const float*)d_in[7];
    const float* w0  = (const float*)d_in[8];
    const float* b0  = (const float*)d_in[9];
    const float* w1  = (const float*)d_in[10];
    const float* b1  = (const float*)d_in[11];
    float* out = (float*)d_out;

    // workspace layout (floats)
    float* ws = (float*)d_ws;
    float*  Wmf0f = ws;                  // 147456
    float*  Wmf1f = Wmf0f + 147456;      // 147456
    float*  Xin0f = Wmf1f + 147456;      // 524288
    float*  Xin1f = Xin0f + 524288;      // 131072
    float*  base0 = Xin1f + 131072;      // 131072 (2b*16off*4096)
    float*  base1 = base0 + 131072;      // 8192   (2b*4off*1024)
    float*  Y0    = base1 + 8192;        // 3211264
    float*  Y1    = Y0 + 3211264;        // 1605632   total 5906432 f = 23.6 MB
    // corr slice buffers alias the Y region (consumed by reduce before conv writes Y)
    float*  slc0  = Y0;                  // 32 chunks * 2b*16off*4096 = 4194304
    float*  slc1  = Y0 + 4194304;        // 64 chunks * 2b*4off*1024  = 524288  (<= 4816896 total ok)
    ushort* Wmf0 = (ushort*)Wmf0f;
    ushort* Wmf1 = (ushort*)Wmf1f;
    ushort* Xin0 = (ushort*)Xin0f;
    ushort* Xin1 = (ushort*)Xin1f;

    // level 0: C=512, CC=16 -> 32 chunks; level 1: C=1024, CC=16 -> 64 chunks
    corr_kernel<512, 16, 64, 64, 4, 2, 2><<<dim3(4, 2, 32), 256, 0, stream>>>(x0, xp0, slc0);
    corr_kernel<1024, 16, 32, 32, 2, 1, 4><<<dim3(1, 2, 64), 256, 0, stream>>>(x1, xp1, slc1);

    reduce_kernel<32, 131072><<<128, 256, 0, stream>>>(slc0, base0);
    reduce_kernel<64, 8192><<<8, 256, 0, stream>>>(slc1, base1);

    wprep_kernel<<<dim3(1152, 2), 256, 0, stream>>>(w0, w1, Wmf0, Wmf1);

    xbuild_kernel<64, 64, 2, 1, 4, 2><<<512, 256, 0, stream>>>(base0, h0, Xin0);
    xbuild_kernel<32, 32, 4, 2, 2, 1><<<128, 256, 0, stream>>>(base1, h1, Xin1);

    convmf_kernel<64, 64, 2, 64, 4, 72><<<dim3(32, 4, 4), 256, 0, stream>>>(Xin0, Wmf0, Y0);
    convmf_kernel<32, 32, 4, 32, 2, 40><<<dim3(8, 4, 8), 256, 0, stream>>>(Xin1, Wmf1, Y1);

    lstm_kernel<2, 4096><<<1568, 256, 0, stream>>>(Y0, b0, c0, out + 0,      out + 401408);
    lstm_kernel<4, 1024><<<392,  256, 0, stream>>>(Y1, b1, c1, out + 802816, out + 903168);
}